// Round 17
// baseline (72.213 us; speedup 1.0000x reference)
//
#include <hip/hip_runtime.h>
#include <hip/hip_bf16.h>

#define S_LEN  1024
#define BATCH  4
#define DMODEL 1024
#define NHEAD  16
#define DHEAD  64
#define NROWS  (S_LEN*BATCH)   // 4096

typedef __bf16 bf16;
typedef __bf16 bf16x2 __attribute__((ext_vector_type(2)));
typedef __bf16 bf16x4 __attribute__((ext_vector_type(4)));
typedef __bf16 bf16x8 __attribute__((ext_vector_type(8)));
typedef float  f32x4  __attribute__((ext_vector_type(4)));
typedef float  f32x16 __attribute__((ext_vector_type(16)));

#define AS1 __attribute__((address_space(1)))
#define AS3 __attribute__((address_space(3)))

#define QSCALE  0.18033688011112042f   // 0.125 * log2(e)

__device__ __forceinline__ void gload16(const bf16* g, bf16* l) {
  __builtin_amdgcn_global_load_lds((const AS1 void*)g, (AS3 void*)l, 16, 0, 0);
}

__device__ __forceinline__ float fast_exp2(float x) {
#if __has_builtin(__builtin_amdgcn_exp2f)
  return __builtin_amdgcn_exp2f(x);
#else
  return exp2f(x);
#endif
}

// ---------------- fused fp32 -> bf16 convert ----------------
__global__ __launch_bounds__(256) void cvt_all(
    const float* __restrict__ hs, const float* __restrict__ wq,
    const float* __restrict__ wk, const float* __restrict__ wv,
    bf16* __restrict__ Xb, bf16* __restrict__ Wb)
{
  const int b = blockIdx.x;
  const float* src; bf16* dst; int i;
  if (b < 2048)      { src = hs; dst = Xb;                           i = b*256        + threadIdx.x; }
  else if (b < 2560) { src = wq; dst = Wb;                           i = (b-2048)*256 + threadIdx.x; }
  else if (b < 3072) { src = wk; dst = Wb + (size_t)DMODEL*DMODEL;   i = (b-2560)*256 + threadIdx.x; }
  else               { src = wv; dst = Wb + (size_t)2*DMODEL*DMODEL; i = (b-3072)*256 + threadIdx.x; }
  const float4* s4 = (const float4*)src;
  float4 a = s4[2*i], c = s4[2*i+1];
  bf16x8 o;
  o[0]=(bf16)a.x; o[1]=(bf16)a.y; o[2]=(bf16)a.z; o[3]=(bf16)a.w;
  o[4]=(bf16)c.x; o[5]=(bf16)c.y; o[6]=(bf16)c.z; o[7]=(bf16)c.w;
  ((bf16x8*)dst)[i] = o;
}

// ---------------- fused QKV GEMM, m97 structure (measured ~27-28us) ----------------
#define BM 128
#define BN 128
#define BK 32

__global__ __launch_bounds__(256) void qkv_gemm(
    const bf16* __restrict__ X, const bf16* __restrict__ Wcat,
    const float* __restrict__ bq, const float* __restrict__ bk, const float* __restrict__ bv,
    bf16* __restrict__ Qo, bf16* __restrict__ Ko, bf16* __restrict__ Vo)
{
  __shared__ __align__(16) bf16 As[BM*BK];   // 8 KB linear
  __shared__ __align__(16) bf16 Bs[BN*BK];   // 8 KB

  const int tid  = threadIdx.x;
  const int row0 = blockIdx.x * BM;
  const int col0 = blockIdx.y * BN;
  const int wsel = col0 >> 10;
  const int coln = col0 & 1023;

  const int wv   = tid >> 6;
  const int lane = tid & 63;
  const int lg   = lane >> 4;
  const int lr   = lane & 15;
  const int wr   = (wv >> 1) << 6;
  const int wc   = (wv & 1) << 6;

  const int c0 = tid, c1 = tid + 256;
  const size_t gA0 = (size_t)(row0 + (c0>>2))*DMODEL + (size_t)((c0&3)<<3);
  const size_t gA1 = (size_t)(row0 + (c1>>2))*DMODEL + (size_t)((c1&3)<<3);
  const size_t gB0 = (size_t)(col0 + (c0>>2))*DMODEL + (size_t)((c0&3)<<3);
  const size_t gB1 = (size_t)(col0 + (c1>>2))*DMODEL + (size_t)((c1&3)<<3);
  const int wb = (tid >> 6) << 6;
  bf16* lA0 = As + (size_t)wb*8;
  bf16* lA1 = As + (size_t)(wb+256)*8;
  bf16* lB0 = Bs + (size_t)wb*8;
  bf16* lB1 = Bs + (size_t)(wb+256)*8;

  f32x4 acc[4][4];
  #pragma unroll
  for (int mi=0; mi<4; ++mi)
    #pragma unroll
    for (int ni=0; ni<4; ++ni)
      acc[mi][ni] = (f32x4){0.f,0.f,0.f,0.f};

  for (int k0 = 0; k0 < DMODEL; k0 += BK) {
    __syncthreads();
    gload16(X    + gA0 + k0, lA0);
    gload16(X    + gA1 + k0, lA1);
    gload16(Wcat + gB0 + k0, lB0);
    gload16(Wcat + gB1 + k0, lB1);
    __syncthreads();

    bf16x8 af[4], bfr[4];
    #pragma unroll
    for (int mi=0; mi<4; ++mi)
      af[mi] = *(const bf16x8*)&As[(wr + mi*16 + lr)*BK + lg*8];
    #pragma unroll
    for (int ni=0; ni<4; ++ni)
      bfr[ni] = *(const bf16x8*)&Bs[(wc + ni*16 + lr)*BK + lg*8];

    #pragma unroll
    for (int mi=0; mi<4; ++mi)
      #pragma unroll
      for (int ni=0; ni<4; ++ni)
        acc[mi][ni] = __builtin_amdgcn_mfma_f32_16x16x32_bf16(af[mi], bfr[ni], acc[mi][ni], 0, 0, 0);
  }

  const float* bias = (wsel==0) ? bq : ((wsel==1) ? bk : bv);
  bf16* Out = (wsel==0) ? Qo : ((wsel==1) ? Ko : Vo);
  const float oscale = (wsel==0) ? QSCALE : 1.0f;   // fold 0.125*log2e into Q

  #pragma unroll
  for (int ni=0; ni<4; ++ni) {
    const int co = coln + wc + ni*16 + lr;
    const float bias_v = bias[co];
    const int h  = co >> 6;
    const int dh = co & 63;
    #pragma unroll
    for (int mi=0; mi<4; ++mi) {
      #pragma unroll
      for (int p=0; p<4; ++p) {
        const int gr = row0 + wr + mi*16 + lg*4 + p;
        const int s_ = gr >> 2;
        const int b_ = gr & 3;
        Out[((size_t)(b_*NHEAD + h)*S_LEN + s_)*DHEAD + dh] = (bf16)((acc[mi][ni][p] + bias_v) * oscale);
      }
    }
  }
}

// ---------------- MFMA flash attention: r16 body + T15 half-tile software pipeline ----------------
// 4 waves x 32 q-rows, QBLK=128, KVB=64, TRIPLE-buffered K/V, XOR chunk-swizzle,
// zero-shuffle P, swapped QK^T, mask-as-C-init. QK of half-tile g+1 is issued BEFORE
// softmax(g)+PV(g) so MFMA (QK-next) and VALU (SM-cur) overlap. 1 barrier per tile.
#define QBLK 128
#define LSW(row, chunk) (((row)<<6) + ((((chunk) ^ ((row)&7)))<<3))

__global__ __launch_bounds__(256, 2) void attn_mfma(
    const bf16* __restrict__ Q, const bf16* __restrict__ K, const bf16* __restrict__ V,
    const float* __restrict__ mask, float* __restrict__ out)
{
  __shared__ __align__(16) bf16 Ks[3][64*64];   // 24 KB
  __shared__ __align__(16) bf16 Vt[3][64*64];   // 24 KB (V^T, swizzled)
  __shared__ float Mskf[S_LEN];                 //  4 KB
  __shared__ float Linv[4][32];                 // 512 B

  const int bh   = blockIdx.x;
  const int b_   = bh >> 4;
  const int h_   = bh & 15;
  const int tid  = threadIdx.x;
  const int wv   = tid >> 6;             // 0..3
  const int lane = tid & 63;
  const int l31  = lane & 31;
  const int hh   = lane >> 5;            // 0/1
  const int q0   = blockIdx.y * QBLK;

  // ---- stage mask row (raw f32; -1e4 additive underflows exp2 to 0) ----
  *(float4*)&Mskf[tid*4] = *(const float4*)&mask[(size_t)b_*S_LEN + tid*4];

  // ---- Q B-frags from global (pre-scaled by QSCALE in gemm): q = lane&31 ----
  const bf16* Qp = Q + ((size_t)bh*S_LEN + q0 + wv*32 + l31)*DHEAD;
  bf16x8 qb[4];
  #pragma unroll
  for (int dk=0; dk<4; ++dk) qb[dk] = *(const bf16x8*)&Qp[dk*16 + hh*8];

  const bf16* Kb = K + (size_t)bh*S_LEN*DHEAD;
  const bf16* Vb = V + (size_t)bh*S_LEN*DHEAD;

  // staging maps (256 threads)
  const int krow = tid >> 2, kch = tid & 3;   // K: row, chunks kch & kch+4
  const int vrow = tid & 63, vcb = tid >> 6;  // V: row=lane, 16 cols starting vcb*16

  bf16x8 kr0, kr1, vr0, vr1;   // in-flight staging regs

  auto stage_load = [&](int t) {
    const size_t nb = (size_t)t*64;
    kr0 = *(const bf16x8*)&Kb[(nb+krow)*DHEAD + kch*8];
    kr1 = *(const bf16x8*)&Kb[(nb+krow)*DHEAD + kch*8 + 32];
    vr0 = *(const bf16x8*)&Vb[(nb+vrow)*DHEAD + vcb*16];
    vr1 = *(const bf16x8*)&Vb[(nb+vrow)*DHEAD + vcb*16 + 8];
  };
  auto stage_write = [&](bf16* Kd, bf16* Vd) {
    *(bf16x8*)&Kd[LSW(krow, kch)]   = kr0;
    *(bf16x8*)&Kd[LSW(krow, kch+4)] = kr1;
    #pragma unroll
    for (int i=0;i<8;++i) {
      const int d0 = vcb*16 + i, d1 = d0 + 8;
      Vd[(d0<<6) + (((vrow>>3) ^ (d0&7))<<3) + (vrow&7)] = vr0[i];
      Vd[(d1<<6) + (((vrow>>3) ^ (d1&7))<<3) + (vrow&7)] = vr1[i];
    }
  };

  f32x16 ctx[2];
  ctx[0] = (f32x16)0.f; ctx[1] = (f32x16)0.f;
  f32x4 lsum4 = (f32x4){0.f,0.f,0.f,0.f};

  // QK^T half-tile: sacc = mask-C-init; 4 MFMAs over dh
  auto qk_half = [&](f32x16& s, const bf16* Kbuf, int mbase, int tt) {
    #pragma unroll
    for (int g4=0; g4<4; ++g4) {
      const f32x4 m4 = *(const f32x4*)&Mskf[mbase + 8*g4 + 4*hh];
      s[4*g4+0]=m4[0]; s[4*g4+1]=m4[1]; s[4*g4+2]=m4[2]; s[4*g4+3]=m4[3];
    }
    const int row = tt*32 + l31;
    __builtin_amdgcn_s_setprio(1);
    #pragma unroll
    for (int dk=0; dk<4; ++dk) {
      bf16x8 ka = *(const bf16x8*)&Kbuf[LSW(row, dk*2 + hh)];
      s = __builtin_amdgcn_mfma_f32_32x32x16_bf16(ka, qb[dk], s, 0,0,0);
    }
    __builtin_amdgcn_s_setprio(0);
  };

  // softmax-finish + PV for one half-tile
  auto sm_pv = [&](const f32x16& s, const bf16* Vc, int tt) {
    float pe[16];
    #pragma unroll
    for (int e=0; e<16; ++e) { pe[e] = fast_exp2(s[e]); lsum4[e&3] += pe[e]; }
    bf16x8 pf[2];
    {
      union { bf16x2 h2[8]; bf16x8 v[2]; } u;
      #pragma unroll
      for (int j=0; j<8; ++j) { bf16x2 p2; p2[0]=(bf16)pe[2*j]; p2[1]=(bf16)pe[2*j+1]; u.h2[j]=p2; }
      pf[0] = u.v[0]; pf[1] = u.v[1];
    }
    __builtin_amdgcn_s_setprio(1);
    #pragma unroll
    for (int nt=0; nt<2; ++nt) {
      const int drow = nt*32 + l31;
      const int dbase = (drow<<6) + 4*hh;
      const int dsw = (drow&7);
      #pragma unroll
      for (int kk=0; kk<2; ++kk) {
        const int lc = tt*4 + kk*2;
        bf16x4 lo = *(const bf16x4*)&Vc[dbase + (((lc  ) ^ dsw)<<3)];
        bf16x4 hi = *(const bf16x4*)&Vc[dbase + (((lc+1) ^ dsw)<<3)];
        bf16x8 vb;
        #pragma unroll
        for (int j=0; j<4; ++j) { vb[j]=lo[j]; vb[4+j]=hi[j]; }
        ctx[nt] = __builtin_amdgcn_mfma_f32_32x32x16_bf16(pf[kk], vb, ctx[nt], 0,0,0);
      }
    }
    __builtin_amdgcn_s_setprio(0);
  };

  // ---- prologue: stage tiles 0 and 1; QK(half 0) ahead ----
  stage_load(0);
  stage_write(&Ks[0][0], &Vt[0][0]);
  stage_load(1);
  __syncthreads();                       // tile0 + Mskf visible
  stage_write(&Ks[1][0], &Vt[1][0]);     // buf1 (no readers yet)

  f32x16 sA, sB;
  qk_half(sA, &Ks[0][0], 0, 0);          // QK(g=0), reads buf0 only
  __syncthreads();                       // tile1 visible

  // ---- main loop: 16 tiles, 2 half-tiles each; QK runs one half ahead ----
  for (int t = 0; t < 16; ++t) {
    const bf16* Kc = &Ks[t%3][0];
    const bf16* Vc = &Vt[t%3][0];

    if (t < 14) stage_load(t+2);         // globals in flight under compute

    // half g=2t: issue QK(g+1) [MFMA] then finish SM(g)+PV(g) [VALU+MFMA]
    qk_half(sB, Kc, t*64 + 32, 1);
    sm_pv(sA, Vc, 0);

    // half g=2t+1: issue QK(g+1) = next tile's first half
    if (t < 15) qk_half(sA, &Ks[(t+1)%3][0], (t+1)*64, 0);
    sm_pv(sB, Vc, 1);

    if (t < 14) stage_write(&Ks[(t+2)%3][0], &Vt[(t+2)%3][0]);
    __syncthreads();
  }

  // ---- lsum: combine partials, partner-half add, distribute via per-wave LDS ----
  float lsum = (lsum4[0] + lsum4[1]) + (lsum4[2] + lsum4[3]);
  const float tot = lsum + __shfl_xor(lsum, 32);
  if (lane < 32) Linv[wv][l31] = 1.f / tot;
  f32x4 inv4[4];
  #pragma unroll
  for (int g4=0; g4<4; ++g4) inv4[g4] = *(const f32x4*)&Linv[wv][8*g4 + 4*hh];

  // ---- write out: out[qg][b][h*64 + nt*32 + (lane&31)] ----
  float* op = out + ((size_t)(q0 + wv*32)*BATCH + b_)*DMODEL + h_*DHEAD + l31;
  #pragma unroll
  for (int e=0; e<16; ++e) {
    const int qe = (e&3) + 8*(e>>2) + 4*hh;
    const float inv = inv4[e>>2][e&3];
    float* oq = op + (size_t)qe*BATCH*DMODEL;
    oq[0]  = ctx[0][e] * inv;
    oq[32] = ctx[1][e] * inv;
  }
}

// ---------------- launch ----------------
extern "C" void kernel_launch(void* const* d_in, const int* in_sizes, int n_in,
                              void* d_out, int out_size, void* d_ws, size_t ws_size,
                              hipStream_t stream) {
  const float* hs   = (const float*)d_in[0];
  const float* mask = (const float*)d_in[1];
  const float* Wq   = (const float*)d_in[2];
  const float* bq   = (const float*)d_in[3];
  const float* Wk   = (const float*)d_in[4];
  const float* bk   = (const float*)d_in[5];
  const float* Wv   = (const float*)d_in[6];
  const float* bv   = (const float*)d_in[7];
  float* out = (float*)d_out;

  char* ws = (char*)d_ws;
  bf16* Xb = (bf16*)ws;                               // 8 MB
  bf16* Wb = Xb + (size_t)NROWS*DMODEL;               // 6 MB
  bf16* Qw = Wb + (size_t)3*DMODEL*DMODEL;            // 8 MB
  bf16* Kw = Qw + (size_t)NROWS*DMODEL;               // 8 MB
  bf16* Vw = Kw + (size_t)NROWS*DMODEL;               // 8 MB

  cvt_all<<<3584, 256, 0, stream>>>(hs, Wq, Wk, Wv, Xb, Wb);

  qkv_gemm<<<dim3(NROWS/BM, 3*DMODEL/BN), 256, 0, stream>>>(Xb, Wb, bq, bk, bv, Qw, Kw, Vw);

  attn_mfma<<<dim3(BATCH*NHEAD, S_LEN/QBLK), 256, 0, stream>>>(Qw, Kw, Vw, mask, out);
}

// Round 18
// 71.081 us; speedup vs baseline: 1.0159x; 1.0159x over previous
//
#include <hip/hip_runtime.h>
#include <hip/hip_bf16.h>

#define S_LEN  1024
#define BATCH  4
#define DMODEL 1024
#define NHEAD  16
#define DHEAD  64
#define NROWS  (S_LEN*BATCH)   // 4096

typedef __bf16 bf16;
typedef __bf16 bf16x2 __attribute__((ext_vector_type(2)));
typedef __bf16 bf16x4 __attribute__((ext_vector_type(4)));
typedef __bf16 bf16x8 __attribute__((ext_vector_type(8)));
typedef float  f32x4  __attribute__((ext_vector_type(4)));
typedef float  f32x16 __attribute__((ext_vector_type(16)));

#define AS1 __attribute__((address_space(1)))
#define AS3 __attribute__((address_space(3)))

#define QSCALE  0.18033688011112042f   // 0.125 * log2(e)

__device__ __forceinline__ void gload16(const bf16* g, bf16* l) {
  __builtin_amdgcn_global_load_lds((const AS1 void*)g, (AS3 void*)l, 16, 0, 0);
}

__device__ __forceinline__ float fast_exp2(float x) {
#if __has_builtin(__builtin_amdgcn_exp2f)
  return __builtin_amdgcn_exp2f(x);
#else
  return exp2f(x);
#endif
}

// ---------------- fused fp32 -> bf16 convert ----------------
__global__ __launch_bounds__(256) void cvt_all(
    const float* __restrict__ hs, const float* __restrict__ wq,
    const float* __restrict__ wk, const float* __restrict__ wv,
    bf16* __restrict__ Xb, bf16* __restrict__ Wb)
{
  const int b = blockIdx.x;
  const float* src; bf16* dst; int i;
  if (b < 2048)      { src = hs; dst = Xb;                           i = b*256        + threadIdx.x; }
  else if (b < 2560) { src = wq; dst = Wb;                           i = (b-2048)*256 + threadIdx.x; }
  else if (b < 3072) { src = wk; dst = Wb + (size_t)DMODEL*DMODEL;   i = (b-2560)*256 + threadIdx.x; }
  else               { src = wv; dst = Wb + (size_t)2*DMODEL*DMODEL; i = (b-3072)*256 + threadIdx.x; }
  const float4* s4 = (const float4*)src;
  float4 a = s4[2*i], c = s4[2*i+1];
  bf16x8 o;
  o[0]=(bf16)a.x; o[1]=(bf16)a.y; o[2]=(bf16)a.z; o[3]=(bf16)a.w;
  o[4]=(bf16)c.x; o[5]=(bf16)c.y; o[6]=(bf16)c.z; o[7]=(bf16)c.w;
  ((bf16x8*)dst)[i] = o;
}

// ---------------- fused QKV GEMM, m97 structure (measured ~27-28us) ----------------
#define BM 128
#define BN 128
#define BK 32

__global__ __launch_bounds__(256) void qkv_gemm(
    const bf16* __restrict__ X, const bf16* __restrict__ Wcat,
    const float* __restrict__ bq, const float* __restrict__ bk, const float* __restrict__ bv,
    bf16* __restrict__ Qo, bf16* __restrict__ Ko, bf16* __restrict__ Vo)
{
  __shared__ __align__(16) bf16 As[BM*BK];   // 8 KB linear
  __shared__ __align__(16) bf16 Bs[BN*BK];   // 8 KB

  const int tid  = threadIdx.x;
  const int row0 = blockIdx.x * BM;
  const int col0 = blockIdx.y * BN;
  const int wsel = col0 >> 10;
  const int coln = col0 & 1023;

  const int wv   = tid >> 6;
  const int lane = tid & 63;
  const int lg   = lane >> 4;
  const int lr   = lane & 15;
  const int wr   = (wv >> 1) << 6;
  const int wc   = (wv & 1) << 6;

  const int c0 = tid, c1 = tid + 256;
  const size_t gA0 = (size_t)(row0 + (c0>>2))*DMODEL + (size_t)((c0&3)<<3);
  const size_t gA1 = (size_t)(row0 + (c1>>2))*DMODEL + (size_t)((c1&3)<<3);
  const size_t gB0 = (size_t)(col0 + (c0>>2))*DMODEL + (size_t)((c0&3)<<3);
  const size_t gB1 = (size_t)(col0 + (c1>>2))*DMODEL + (size_t)((c1&3)<<3);
  const int wb = (tid >> 6) << 6;
  bf16* lA0 = As + (size_t)wb*8;
  bf16* lA1 = As + (size_t)(wb+256)*8;
  bf16* lB0 = Bs + (size_t)wb*8;
  bf16* lB1 = Bs + (size_t)(wb+256)*8;

  f32x4 acc[4][4];
  #pragma unroll
  for (int mi=0; mi<4; ++mi)
    #pragma unroll
    for (int ni=0; ni<4; ++ni)
      acc[mi][ni] = (f32x4){0.f,0.f,0.f,0.f};

  for (int k0 = 0; k0 < DMODEL; k0 += BK) {
    __syncthreads();
    gload16(X    + gA0 + k0, lA0);
    gload16(X    + gA1 + k0, lA1);
    gload16(Wcat + gB0 + k0, lB0);
    gload16(Wcat + gB1 + k0, lB1);
    __syncthreads();

    bf16x8 af[4], bfr[4];
    #pragma unroll
    for (int mi=0; mi<4; ++mi)
      af[mi] = *(const bf16x8*)&As[(wr + mi*16 + lr)*BK + lg*8];
    #pragma unroll
    for (int ni=0; ni<4; ++ni)
      bfr[ni] = *(const bf16x8*)&Bs[(wc + ni*16 + lr)*BK + lg*8];

    #pragma unroll
    for (int mi=0; mi<4; ++mi)
      #pragma unroll
      for (int ni=0; ni<4; ++ni)
        acc[mi][ni] = __builtin_amdgcn_mfma_f32_16x16x32_bf16(af[mi], bfr[ni], acc[mi][ni], 0, 0, 0);
  }

  const float* bias = (wsel==0) ? bq : ((wsel==1) ? bk : bv);
  bf16* Out = (wsel==0) ? Qo : ((wsel==1) ? Ko : Vo);
  const float oscale = (wsel==0) ? QSCALE : 1.0f;   // fold 0.125*log2e into Q

  #pragma unroll
  for (int ni=0; ni<4; ++ni) {
    const int co = coln + wc + ni*16 + lr;
    const float bias_v = bias[co];
    const int h  = co >> 6;
    const int dh = co & 63;
    #pragma unroll
    for (int mi=0; mi<4; ++mi) {
      #pragma unroll
      for (int p=0; p<4; ++p) {
        const int gr = row0 + wr + mi*16 + lg*4 + p;
        const int s_ = gr >> 2;
        const int b_ = gr & 3;
        Out[((size_t)(b_*NHEAD + h)*S_LEN + s_)*DHEAD + dh] = (bf16)((acc[mi][ni][p] + bias_v) * oscale);
      }
    }
  }
}

// ---------------- MFMA flash attention: r7 body (best measured, ~35us) ----------------
// 4 waves x 32 q-rows, QBLK=128, dbuf K/V (KVB=64), XOR chunk-swizzle, zero-shuffle P,
// swapped QK^T (D[t][q], q=lane&31), f32 additive mask in LDS (exp2 underflow -> 0).
#define QBLK 128
#define LSW(row, chunk) (((row)<<6) + ((((chunk) ^ ((row)&7)))<<3))

__global__ __launch_bounds__(256, 2) void attn_mfma(
    const bf16* __restrict__ Q, const bf16* __restrict__ K, const bf16* __restrict__ V,
    const float* __restrict__ mask, float* __restrict__ out)
{
  __shared__ __align__(16) bf16 Ks[2][64*64];   // 16 KB
  __shared__ __align__(16) bf16 Vt[2][64*64];   // 16 KB (V^T, swizzled)
  __shared__ float Mskf[S_LEN];                 //  4 KB
  __shared__ float Linv[4][32];                 // 512 B

  const int bh   = blockIdx.x;
  const int b_   = bh >> 4;
  const int h_   = bh & 15;
  const int tid  = threadIdx.x;
  const int wv   = tid >> 6;             // 0..3
  const int lane = tid & 63;
  const int l31  = lane & 31;
  const int hh   = lane >> 5;            // 0/1
  const int q0   = blockIdx.y * QBLK;

  // ---- stage mask row (raw f32; -1e4 additive underflows exp2 to 0) ----
  *(float4*)&Mskf[tid*4] = *(const float4*)&mask[(size_t)b_*S_LEN + tid*4];

  // ---- Q B-frags from global (pre-scaled by QSCALE in gemm): q = lane&31 ----
  const bf16* Qp = Q + ((size_t)bh*S_LEN + q0 + wv*32 + l31)*DHEAD;
  bf16x8 qb[4];
  #pragma unroll
  for (int dk=0; dk<4; ++dk) qb[dk] = *(const bf16x8*)&Qp[dk*16 + hh*8];

  const bf16* Kb = K + (size_t)bh*S_LEN*DHEAD;
  const bf16* Vb = V + (size_t)bh*S_LEN*DHEAD;

  // staging maps (256 threads)
  const int krow = tid >> 2, kch = tid & 3;   // K: row, chunks kch & kch+4
  const int vrow = tid & 63, vcb = tid >> 6;  // V: row=lane, 16 cols starting vcb*16

  // ---- prologue: stage tile 0 ----
  bf16x8 kr0 = *(const bf16x8*)&Kb[(size_t)krow*DHEAD + kch*8];
  bf16x8 kr1 = *(const bf16x8*)&Kb[(size_t)krow*DHEAD + kch*8 + 32];
  bf16x8 vr0 = *(const bf16x8*)&Vb[(size_t)vrow*DHEAD + vcb*16];
  bf16x8 vr1 = *(const bf16x8*)&Vb[(size_t)vrow*DHEAD + vcb*16 + 8];
  {
    *(bf16x8*)&Ks[0][LSW(krow, kch)]   = kr0;
    *(bf16x8*)&Ks[0][LSW(krow, kch+4)] = kr1;
    #pragma unroll
    for (int i=0;i<8;++i) {
      const int d0 = vcb*16 + i, d1 = d0 + 8;
      Vt[0][(d0<<6) + (((vrow>>3) ^ (d0&7))<<3) + (vrow&7)] = vr0[i];
      Vt[0][(d1<<6) + (((vrow>>3) ^ (d1&7))<<3) + (vrow&7)] = vr1[i];
    }
  }
  __syncthreads();

  f32x16 ctx[2];
  ctx[0] = (f32x16)0.f; ctx[1] = (f32x16)0.f;
  float lsum = 0.f;

  for (int t = 0; t < 16; ++t) {
    const bf16* Kc = Ks[t & 1];
    const bf16* Vc = Vt[t & 1];

    // issue next tile's global loads early
    if (t < 15) {
      const size_t nb = (size_t)(t+1)*64;
      kr0 = *(const bf16x8*)&Kb[(nb+krow)*DHEAD + kch*8];
      kr1 = *(const bf16x8*)&Kb[(nb+krow)*DHEAD + kch*8 + 32];
      vr0 = *(const bf16x8*)&Vb[(nb+vrow)*DHEAD + vcb*16];
      vr1 = *(const bf16x8*)&Vb[(nb+vrow)*DHEAD + vcb*16 + 8];
    }

    // ---- QK^T (swapped): D[t][q], 2 t-tiles of 32, contraction dh=64 ----
    f32x16 sacc[2];
    sacc[0] = (f32x16)0.f; sacc[1] = (f32x16)0.f;
    __builtin_amdgcn_s_setprio(1);
    #pragma unroll
    for (int tt=0; tt<2; ++tt) {
      const int row = tt*32 + l31;
      #pragma unroll
      for (int dk=0; dk<4; ++dk) {
        bf16x8 ka = *(const bf16x8*)&Kc[LSW(row, dk*2 + hh)];
        sacc[tt] = __builtin_amdgcn_mfma_f32_32x32x16_bf16(ka, qb[dk], sacc[tt], 0,0,0);
      }
    }
    __builtin_amdgcn_s_setprio(0);

    // ---- softmax: p = exp2(s + m); lsum VALU; pack to PV A-frags in-lane ----
    const int tb = t*64;
    bf16x8 pf[2][2];
    #pragma unroll
    for (int tt=0; tt<2; ++tt) {
      f32x4 mv[4];
      #pragma unroll
      for (int g=0; g<4; ++g)
        mv[g] = *(const f32x4*)&Mskf[tb + tt*32 + 8*g + 4*hh];
      float pe[16];
      #pragma unroll
      for (int e=0; e<16; ++e) {
        pe[e] = fast_exp2(sacc[tt][e] + mv[e>>2][e&3]);
        lsum += pe[e];
      }
      union { bf16x2 h2[8]; bf16x8 v[2]; } u;
      #pragma unroll
      for (int j=0; j<8; ++j) { bf16x2 p2; p2[0]=(bf16)pe[2*j]; p2[1]=(bf16)pe[2*j+1]; u.h2[j]=p2; }
      pf[tt][0] = u.v[0]; pf[tt][1] = u.v[1];
    }

    // ---- PV: O[q][d] += P * V ; B-frags via slot->t map (2x b64 each) ----
    __builtin_amdgcn_s_setprio(1);
    #pragma unroll
    for (int nt=0; nt<2; ++nt) {
      const int drow = nt*32 + l31;
      const int dbase = (drow<<6) + 4*hh;
      const int dsw = (drow&7);
      #pragma unroll
      for (int tt=0; tt<2; ++tt) {
        #pragma unroll
        for (int kk=0; kk<2; ++kk) {
          const int lc = tt*4 + kk*2;
          bf16x4 lo = *(const bf16x4*)&Vc[dbase + (((lc  ) ^ dsw)<<3)];
          bf16x4 hi = *(const bf16x4*)&Vc[dbase + (((lc+1) ^ dsw)<<3)];
          bf16x8 vb;
          #pragma unroll
          for (int j=0; j<4; ++j) { vb[j]=lo[j]; vb[4+j]=hi[j]; }
          ctx[nt] = __builtin_amdgcn_mfma_f32_32x32x16_bf16(pf[tt][kk], vb, ctx[nt], 0,0,0);
        }
      }
    }
    __builtin_amdgcn_s_setprio(0);

    // ---- stage next tile into other buffer ----
    if (t < 15) {
      bf16* Kn = (bf16*)Ks[(t+1) & 1];
      bf16* Vn = (bf16*)Vt[(t+1) & 1];
      *(bf16x8*)&Kn[LSW(krow, kch)]   = kr0;
      *(bf16x8*)&Kn[LSW(krow, kch+4)] = kr1;
      #pragma unroll
      for (int i=0;i<8;++i) {
        const int d0 = vcb*16 + i, d1 = d0 + 8;
        Vn[(d0<<6) + (((vrow>>3) ^ (d0&7))<<3) + (vrow&7)] = vr0[i];
        Vn[(d1<<6) + (((vrow>>3) ^ (d1&7))<<3) + (vrow&7)] = vr1[i];
      }
    }
    __syncthreads();
  }

  // ---- lsum: partner-half add, distribute 1/lsum via per-wave LDS row ----
  const float tot = lsum + __shfl_xor(lsum, 32);
  if (lane < 32) Linv[wv][l31] = 1.f / tot;
  f32x4 inv4[4];
  #pragma unroll
  for (int g4=0; g4<4; ++g4) inv4[g4] = *(const f32x4*)&Linv[wv][8*g4 + 4*hh];

  // ---- write out: out[qg][b][h*64 + nt*32 + (lane&31)] ----
  float* op = out + ((size_t)(q0 + wv*32)*BATCH + b_)*DMODEL + h_*DHEAD + l31;
  #pragma unroll
  for (int e=0; e<16; ++e) {
    const int qe = (e&3) + 8*(e>>2) + 4*hh;
    const float inv = inv4[e>>2][e&3];
    float* oq = op + (size_t)qe*BATCH*DMODEL;
    oq[0]  = ctx[0][e] * inv;
    oq[32] = ctx[1][e] * inv;
  }
}

// ---------------- launch ----------------
extern "C" void kernel_launch(void* const* d_in, const int* in_sizes, int n_in,
                              void* d_out, int out_size, void* d_ws, size_t ws_size,
                              hipStream_t stream) {
  const float* hs   = (const float*)d_in[0];
  const float* mask = (const float*)d_in[1];
  const float* Wq   = (const float*)d_in[2];
  const float* bq   = (const float*)d_in[3];
  const float* Wk   = (const float*)d_in[4];
  const float* bk   = (const float*)d_in[5];
  const float* Wv   = (const float*)d_in[6];
  const float* bv   = (const float*)d_in[7];
  float* out = (float*)d_out;

  char* ws = (char*)d_ws;
  bf16* Xb = (bf16*)ws;                               // 8 MB
  bf16* Wb = Xb + (size_t)NROWS*DMODEL;               // 6 MB
  bf16* Qw = Wb + (size_t)3*DMODEL*DMODEL;            // 8 MB
  bf16* Kw = Qw + (size_t)NROWS*DMODEL;               // 8 MB
  bf16* Vw = Kw + (size_t)NROWS*DMODEL;               // 8 MB

  cvt_all<<<3584, 256, 0, stream>>>(hs, Wq, Wk, Wv, Xb, Wb);

  qkv_gemm<<<dim3(NROWS/BM, 3*DMODEL/BN), 256, 0, stream>>>(Xb, Wb, bq, bk, bv, Qw, Kw, Vw);

  attn_mfma<<<dim3(BATCH*NHEAD, S_LEN/QBLK), 256, 0, stream>>>(Qw, Kw, Vw, mask, out);
}